// Round 8
// baseline (547.350 us; speedup 1.0000x reference)
//
#include <hip/hip_runtime.h>

#pragma clang fp contract(off)

#define NP 410881  // 641*641

// ---------------------------------------------------------------------------
// Kernel 1: per-slot tables from transformer_class_probs (128 x 134).
// One wave per 8 rows; shuffle-reduce (max, first-index) over 133 cols.
// ---------------------------------------------------------------------------
__global__ __launch_bounds__(1024) void slot_kernel(
    const float* __restrict__ probs, float* __restrict__ cls_pred,
    int* __restrict__ det_idx, unsigned long long* __restrict__ det_mask,
    int* __restrict__ num_det) {
  __shared__ float s_val[128];
  __shared__ int s_arg[128];
  __shared__ int s_tot0;
  int tid = threadIdx.x;
  int wv = tid >> 6, lane = tid & 63;

  float bvv[8];
  int bii[8];
#pragma unroll
  for (int k = 0; k < 8; ++k) {  // preload: 24 outstanding loads per lane
    int r = wv * 8 + k;
    const float* row = probs + r * 134;
    float v0 = row[lane];
    float v1 = row[lane + 64];
    float v2 = (lane < 5) ? row[lane + 128] : -1.0f;
    float bv = v0;
    int bi = lane;
    if (v1 > bv) { bv = v1; bi = lane + 64; }
    if (v2 > bv) { bv = v2; bi = lane + 128; }
    bvv[k] = bv; bii[k] = bi;
  }
#pragma unroll
  for (int k = 0; k < 8; ++k) {
    float bv = bvv[k];
    int bi = bii[k];
#pragma unroll
    for (int off = 32; off; off >>= 1) {  // (max, first-idx) butterfly
      float ov = __shfl_xor(bv, off);
      int oi = __shfl_xor(bi, off);
      if (ov > bv || (ov == bv && oi < bi)) { bv = ov; bi = oi; }
    }
    if (lane == 0) { s_val[wv * 8 + k] = bv; s_arg[wv * 8 + k] = bi; }
  }
  __syncthreads();

  bool flag = false;
  unsigned long long b = 0;
  if (tid < 128) flag = s_val[tid] >= 0.7f;
  if (wv < 2) b = __ballot(flag);  // wave-uniform branch
  if (tid < 128 && lane == 0) {
    det_mask[wv] = b;
    if (wv == 0) s_tot0 = __popcll(b);
  }
  __syncthreads();
  if (tid < 128) {
    int incl = __popcll(b & ((1ull << lane) - 1)) + (flag ? 1 : 0) +
               (wv ? s_tot0 : 0);
    det_idx[tid] = incl - 1;  // cumsum(det)-1
    cls_pred[tid] = (float)s_arg[tid];
    if (tid == 127) *num_det = incl;
  }
}

// ---------------------------------------------------------------------------
// Kernel 2 (round 8): r5 skeleton (2 px/thread, no LDS, direct float4) +
//  - software-pipelined DOUBLE-BUFFERED batches of 8 channels: 8 loads in
//    flight continuously per wave (r5 post-mortem: each 4-ch batch waited a
//    full ~900-cyc HBM/L3 latency with vmcnt(0) drain -> latency-bound).
//  - XCD band swizzle (r7-proven FETCH reduction): grid 1688 = 8*211,
//    each XCD owns ~211 consecutive tiles (~1.8 MB texel band < 4 MB L2).
//  - __launch_bounds__(128,4): cap VGPR at 128 -> 16-waves/CU tier kept.
// ---------------------------------------------------------------------------
__global__ __launch_bounds__(128, 4) void post_kernel(
    const float* __restrict__ logits, const float* __restrict__ ws_cls,
    const int* __restrict__ ws_didx,
    const unsigned long long* __restrict__ ws_mask,
    const int* __restrict__ ws_ndet, float* __restrict__ out) {
#pragma clang fp contract(off)
  // XCD-band swizzle: bijection on [0,1688); consecutive lin = same XCD.
  int bid = blockIdx.x;
  int lin = (bid & 7) * 211 + (bid >> 3);
  if (lin >= 1681) return;
  int byi = lin / 41, bxi = lin - byi * 41;
  int X0 = bxi << 4, Y0 = byi << 4;

  int tid = threadIdx.x;
  // lane -> pixel pair
  int strip = tid & 7, py = tid >> 3;
  int cx = strip >> 1, h = strip & 1;
  int cy = py >> 2;
  int xa = X0 + (cx << 2) + (h << 1);
  int y = Y0 + py;

  int ndet = *ws_ndet;  // uniform
  if (ndet == 0) {      // reference zeroes everything when nothing detected
    if (y < 641) {
      if (xa < 641) {
        int i0 = y * 641 + xa;
        out[i0] = 1.0f; out[NP + i0] = 0.f; out[2 * NP + i0] = 0.f; out[3 * NP + i0] = 0.f;
      }
      if (xa + 1 < 641) {
        int i1 = y * 641 + xa + 1;
        out[i1] = 1.0f; out[NP + i1] = 0.f; out[2 * NP + i1] = 0.f; out[3 * NP + i1] = 0.f;
      }
    }
    return;
  }

  // texel coordinates (clamped; matches reference x1=min(x0+1,160))
  int tx0 = min((X0 >> 2) + cx, 160);
  int tx1 = min(tx0 + 1, 160);
  int ty0 = min((Y0 >> 2) + cy, 160);
  int ty1 = min(ty0 + 1, 160);
  const float* P00 = logits + ((ty0 * 161 + tx0) << 7);
  const float* P01 = logits + ((ty0 * 161 + tx1) << 7);
  const float* P10 = logits + ((ty1 * 161 + tx0) << 7);
  const float* P11 = logits + ((ty1 * 161 + tx1) << 7);

  float wy = 0.25f * (float)(py & 3);
  float iwy = 1.0f - wy;
  float wx0 = 0.5f * (float)h;
  float wx1 = wx0 + 0.25f;
  float iwx0 = 1.0f - wx0, iwx1 = 1.0f - wx1;

  float m0 = -INFINITY, m1 = -INFINITY;  // final masked max
  int am0 = 0, am1 = 0;                  // final masked argmax (first-index)
  float T0 = 0.f, T1 = 0.f;              // final sum exp(v) over detected
  bool dp0 = true, dp1 = true;           // detected_pixel

  if (ndet == 128) {  // fast path: masked == resized
    // 4 independent accumulator streams: stream j = channels c with c&3==j
    float ms0[4], ms1[4], Ts0[4], Ts1[4];
    int as0[4], as1[4];
#pragma unroll
    for (int j = 0; j < 4; ++j) {
      ms0[j] = -INFINITY; ms1[j] = -INFINITY;
      Ts0[j] = 0.f; Ts1[j] = 0.f;
      as0[j] = 0; as1[j] = 0;
    }
// one channel into stream J; reference op order, contract off
#define CH(A00, A01, A10, A11, CIDX, J)                                        \
  {                                                                            \
    float r0 = (A00) * iwy + (A10) * wy;                                       \
    float r1 = (A01) * iwy + (A11) * wy;                                       \
    float v0 = r0 * iwx0 + r1 * wx0;                                           \
    float v1 = r0 * iwx1 + r1 * wx1;                                           \
    bool g0 = v0 > ms0[J]; ms0[J] = g0 ? v0 : ms0[J]; as0[J] = g0 ? (CIDX) : as0[J]; \
    bool g1 = v1 > ms1[J]; ms1[J] = g1 ? v1 : ms1[J]; as1[J] = g1 ? (CIDX) : as1[J]; \
    Ts0[J] += __expf(v0);                                                      \
    Ts1[J] += __expf(v1);                                                      \
  }
// load one 8-channel batch (8 float4 = 32 VGPRs) starting at channel C
#define LOADB(B, C)                                                            \
  {                                                                            \
    B[0] = *(const float4*)(P00 + (C));                                        \
    B[1] = *(const float4*)(P00 + (C) + 4);                                    \
    B[2] = *(const float4*)(P01 + (C));                                        \
    B[3] = *(const float4*)(P01 + (C) + 4);                                    \
    B[4] = *(const float4*)(P10 + (C));                                        \
    B[5] = *(const float4*)(P10 + (C) + 4);                                    \
    B[6] = *(const float4*)(P11 + (C));                                        \
    B[7] = *(const float4*)(P11 + (C) + 4);                                    \
  }
// compute one 8-channel batch from buffer B at base channel C
#define COMPB(B, C)                                                            \
  {                                                                            \
    CH(B[0].x, B[2].x, B[4].x, B[6].x, (C) + 0, 0);                            \
    CH(B[0].y, B[2].y, B[4].y, B[6].y, (C) + 1, 1);                            \
    CH(B[0].z, B[2].z, B[4].z, B[6].z, (C) + 2, 2);                            \
    CH(B[0].w, B[2].w, B[4].w, B[6].w, (C) + 3, 3);                            \
    CH(B[1].x, B[3].x, B[5].x, B[7].x, (C) + 4, 0);                            \
    CH(B[1].y, B[3].y, B[5].y, B[7].y, (C) + 5, 1);                            \
    CH(B[1].z, B[3].z, B[5].z, B[7].z, (C) + 6, 2);                            \
    CH(B[1].w, B[3].w, B[5].w, B[7].w, (C) + 7, 3);                            \
  }
    float4 A[8], B[8];
    LOADB(A, 0);
#pragma unroll
    for (int k = 0; k < 16; k += 2) {  // 16 batches of 8 channels, dbuf
      LOADB(B, 8 * (k + 1));           // batch k+1 in flight...
      COMPB(A, 8 * k);                 // ...while computing batch k
      if (k + 2 < 16) LOADB(A, 8 * (k + 2));
      COMPB(B, 8 * (k + 1));
    }
#undef COMPB
#undef LOADB
#undef CH
    // exact merge: global max; on value tie, smallest channel index wins
    m0 = ms0[0]; am0 = as0[0]; m1 = ms1[0]; am1 = as1[0];
#pragma unroll
    for (int j = 1; j < 4; ++j) {
      if (ms0[j] > m0 || (ms0[j] == m0 && as0[j] < am0)) { m0 = ms0[j]; am0 = as0[j]; }
      if (ms1[j] > m1 || (ms1[j] == m1 && as1[j] < am1)) { m1 = ms1[j]; am1 = as1[j]; }
    }
    T0 = (Ts0[0] + Ts0[1]) + (Ts0[2] + Ts0[3]);
    T1 = (Ts1[0] + Ts1[1]) + (Ts1[2] + Ts1[3]);
  } else {  // general path (never taken for this input; correctness only)
    unsigned long long mlo = ws_mask[0], mhi = ws_mask[1];
    float rm0 = -INFINITY, rm1 = -INFINITY;
#pragma unroll 4
    for (int c = 0; c < 128; ++c) {
      float a00 = P00[c], a01 = P01[c];
      float a10 = P10[c], a11 = P11[c];
      float r0 = a00 * iwy + a10 * wy;
      float r1 = a01 * iwy + a11 * wy;
      float v0 = r0 * iwx0 + r1 * wx0;
      float v1 = r0 * iwx1 + r1 * wx1;
      rm0 = fmaxf(rm0, v0);
      rm1 = fmaxf(rm1, v1);
      unsigned long long bit = (c < 64) ? (mlo >> c) : (mhi >> (c - 64));
      if (bit & 1) {  // wave-uniform branch
        bool g0 = v0 > m0; m0 = g0 ? v0 : m0; am0 = g0 ? c : am0;
        bool g1 = v1 > m1; m1 = g1 ? v1 : m1; am1 = g1 ? c : am1;
        T0 += __expf(v0);
        T1 += __expf(v1);
      }
    }
    dp0 = (rm0 == m0);
    dp1 = (rm1 == m1);
  }

  // ---- epilogue: conf > 0.4  <=>  exp(m) > 0.4*T  (T > 0, all v bounded)
  float cg0 = ((__expf(m0) > 0.4f * T0) && dp0) ? 1.0f : 0.0f;
  float cg1 = ((__expf(m1) > 0.4f * T1) && dp1) ? 1.0f : 0.0f;
  float sem0 = ws_cls[am0], sem1 = ws_cls[am1];  // L1/L2-cached tables
  float mid0 = (float)(ws_didx[am0] + 1), mid1 = (float)(ws_didx[am1] + 1);
  float th0 = (sem0 < 80.f) ? cg0 : 0.f;
  float st0 = cg0 - th0;
  float th1 = (sem1 < 80.f) ? cg1 : 0.f;
  float st1 = cg1 - th1;

  if (y < 641) {
    if (xa < 641) {
      int i0 = y * 641 + xa;
      out[i0] = mid0; out[NP + i0] = sem0; out[2 * NP + i0] = th0; out[3 * NP + i0] = st0;
    }
    if (xa + 1 < 641) {
      int i1 = y * 641 + xa + 1;
      out[i1] = mid1; out[NP + i1] = sem1; out[2 * NP + i1] = th1; out[3 * NP + i1] = st1;
    }
  }
}

extern "C" void kernel_launch(void* const* d_in, const int* in_sizes, int n_in,
                              void* d_out, int out_size, void* d_ws,
                              size_t ws_size, hipStream_t stream) {
  const float* logits = (const float*)d_in[0];  // (161,161,128) f32
  const float* probs = (const float*)d_in[1];   // (128,134) f32
  float* out = (float*)d_out;

  float* ws_f = (float*)d_ws;
  float* cls_pred = ws_f;                                    // 128 f32
  int* det_idx = (int*)(ws_f + 128);                         // 128 i32
  unsigned long long* det_mask = (unsigned long long*)(ws_f + 256);  // 2 u64
  int* num_det = (int*)(ws_f + 260);                         // 1 i32

  slot_kernel<<<1, 1024, 0, stream>>>(probs, cls_pred, det_idx, det_mask,
                                      num_det);

  // 1681 tiles (41x41 of 16x16), padded to 1688 = 8*211 for XCD banding.
  post_kernel<<<1688, 128, 0, stream>>>(logits, cls_pred, det_idx, det_mask,
                                        num_det, out);
}

// Round 9
// 139.585 us; speedup vs baseline: 3.9213x; 3.9213x over previous
//
#include <hip/hip_runtime.h>

#pragma clang fp contract(off)

#define NP 410881  // 641*641

// ---------------------------------------------------------------------------
// Kernel 1: per-slot tables from transformer_class_probs (128 x 134).
// One wave per 8 rows; shuffle-reduce (max, first-index) over 133 cols.
// ---------------------------------------------------------------------------
__global__ __launch_bounds__(1024) void slot_kernel(
    const float* __restrict__ probs, float* __restrict__ cls_pred,
    int* __restrict__ det_idx, unsigned long long* __restrict__ det_mask,
    int* __restrict__ num_det) {
  __shared__ float s_val[128];
  __shared__ int s_arg[128];
  __shared__ int s_tot0;
  int tid = threadIdx.x;
  int wv = tid >> 6, lane = tid & 63;

  float bvv[8];
  int bii[8];
#pragma unroll
  for (int k = 0; k < 8; ++k) {  // preload: 24 outstanding loads per lane
    int r = wv * 8 + k;
    const float* row = probs + r * 134;
    float v0 = row[lane];
    float v1 = row[lane + 64];
    float v2 = (lane < 5) ? row[lane + 128] : -1.0f;
    float bv = v0;
    int bi = lane;
    if (v1 > bv) { bv = v1; bi = lane + 64; }
    if (v2 > bv) { bv = v2; bi = lane + 128; }
    bvv[k] = bv; bii[k] = bi;
  }
#pragma unroll
  for (int k = 0; k < 8; ++k) {
    float bv = bvv[k];
    int bi = bii[k];
#pragma unroll
    for (int off = 32; off; off >>= 1) {  // (max, first-idx) butterfly
      float ov = __shfl_xor(bv, off);
      int oi = __shfl_xor(bi, off);
      if (ov > bv || (ov == bv && oi < bi)) { bv = ov; bi = oi; }
    }
    if (lane == 0) { s_val[wv * 8 + k] = bv; s_arg[wv * 8 + k] = bi; }
  }
  __syncthreads();

  bool flag = false;
  unsigned long long b = 0;
  if (tid < 128) flag = s_val[tid] >= 0.7f;
  if (wv < 2) b = __ballot(flag);  // wave-uniform branch
  if (tid < 128 && lane == 0) {
    det_mask[wv] = b;
    if (wv == 0) s_tot0 = __popcll(b);
  }
  __syncthreads();
  if (tid < 128) {
    int incl = __popcll(b & ((1ull << lane) - 1)) + (flag ? 1 : 0) +
               (wv ? s_tot0 : 0);
    det_idx[tid] = incl - 1;  // cumsum(det)-1
    cls_pred[tid] = (float)s_arg[tid];
    if (tid == 127) *num_det = incl;
  }
}

// ---------------------------------------------------------------------------
// Kernel 2 (round 9): r8's deep double-buffered pipeline WITHOUT the VGPR
// cap. r8's __launch_bounds__(128,4) capped VGPRs at 64 -> the 16 float4
// buffers spilled to scratch (FETCH 599MB / WRITE 718MB, 489us). Plain
// __launch_bounds__(128) lets VGPRs float (~150-170, still the 3-waves/SIMD
// tier = r5's supply) so the 8-deep in-flight load pipeline actually exists
// in registers. XCD band swizzle kept (r7: FETCH 9.75 -> 7.1 MB).
// ---------------------------------------------------------------------------
__global__ __launch_bounds__(128) void post_kernel(
    const float* __restrict__ logits, const float* __restrict__ ws_cls,
    const int* __restrict__ ws_didx,
    const unsigned long long* __restrict__ ws_mask,
    const int* __restrict__ ws_ndet, float* __restrict__ out) {
#pragma clang fp contract(off)
  // XCD-band swizzle: bijection on [0,1688); consecutive lin = same XCD.
  int bid = blockIdx.x;
  int lin = (bid & 7) * 211 + (bid >> 3);
  if (lin >= 1681) return;
  int byi = lin / 41, bxi = lin - byi * 41;
  int X0 = bxi << 4, Y0 = byi << 4;

  int tid = threadIdx.x;
  // lane -> pixel pair
  int strip = tid & 7, py = tid >> 3;
  int cx = strip >> 1, h = strip & 1;
  int cy = py >> 2;
  int xa = X0 + (cx << 2) + (h << 1);
  int y = Y0 + py;

  int ndet = *ws_ndet;  // uniform
  if (ndet == 0) {      // reference zeroes everything when nothing detected
    if (y < 641) {
      if (xa < 641) {
        int i0 = y * 641 + xa;
        out[i0] = 1.0f; out[NP + i0] = 0.f; out[2 * NP + i0] = 0.f; out[3 * NP + i0] = 0.f;
      }
      if (xa + 1 < 641) {
        int i1 = y * 641 + xa + 1;
        out[i1] = 1.0f; out[NP + i1] = 0.f; out[2 * NP + i1] = 0.f; out[3 * NP + i1] = 0.f;
      }
    }
    return;
  }

  // texel coordinates (clamped; matches reference x1=min(x0+1,160))
  int tx0 = min((X0 >> 2) + cx, 160);
  int tx1 = min(tx0 + 1, 160);
  int ty0 = min((Y0 >> 2) + cy, 160);
  int ty1 = min(ty0 + 1, 160);
  const float* P00 = logits + ((ty0 * 161 + tx0) << 7);
  const float* P01 = logits + ((ty0 * 161 + tx1) << 7);
  const float* P10 = logits + ((ty1 * 161 + tx0) << 7);
  const float* P11 = logits + ((ty1 * 161 + tx1) << 7);

  float wy = 0.25f * (float)(py & 3);
  float iwy = 1.0f - wy;
  float wx0 = 0.5f * (float)h;
  float wx1 = wx0 + 0.25f;
  float iwx0 = 1.0f - wx0, iwx1 = 1.0f - wx1;

  float m0 = -INFINITY, m1 = -INFINITY;  // final masked max
  int am0 = 0, am1 = 0;                  // final masked argmax (first-index)
  float T0 = 0.f, T1 = 0.f;              // final sum exp(v) over detected
  bool dp0 = true, dp1 = true;           // detected_pixel

  if (ndet == 128) {  // fast path: masked == resized
    // 4 independent accumulator streams: stream j = channels c with c&3==j
    float ms0[4], ms1[4], Ts0[4], Ts1[4];
    int as0[4], as1[4];
#pragma unroll
    for (int j = 0; j < 4; ++j) {
      ms0[j] = -INFINITY; ms1[j] = -INFINITY;
      Ts0[j] = 0.f; Ts1[j] = 0.f;
      as0[j] = 0; as1[j] = 0;
    }
// one channel into stream J; reference op order, contract off
#define CH(A00, A01, A10, A11, CIDX, J)                                        \
  {                                                                            \
    float r0 = (A00) * iwy + (A10) * wy;                                       \
    float r1 = (A01) * iwy + (A11) * wy;                                       \
    float v0 = r0 * iwx0 + r1 * wx0;                                           \
    float v1 = r0 * iwx1 + r1 * wx1;                                           \
    bool g0 = v0 > ms0[J]; ms0[J] = g0 ? v0 : ms0[J]; as0[J] = g0 ? (CIDX) : as0[J]; \
    bool g1 = v1 > ms1[J]; ms1[J] = g1 ? v1 : ms1[J]; as1[J] = g1 ? (CIDX) : as1[J]; \
    Ts0[J] += __expf(v0);                                                      \
    Ts1[J] += __expf(v1);                                                      \
  }
// load one 8-channel batch (8 float4 = 32 VGPRs) starting at channel C
#define LOADB(B, C)                                                            \
  {                                                                            \
    B[0] = *(const float4*)(P00 + (C));                                        \
    B[1] = *(const float4*)(P00 + (C) + 4);                                    \
    B[2] = *(const float4*)(P01 + (C));                                        \
    B[3] = *(const float4*)(P01 + (C) + 4);                                    \
    B[4] = *(const float4*)(P10 + (C));                                        \
    B[5] = *(const float4*)(P10 + (C) + 4);                                    \
    B[6] = *(const float4*)(P11 + (C));                                        \
    B[7] = *(const float4*)(P11 + (C) + 4);                                    \
  }
// compute one 8-channel batch from buffer B at base channel C
#define COMPB(B, C)                                                            \
  {                                                                            \
    CH(B[0].x, B[2].x, B[4].x, B[6].x, (C) + 0, 0);                            \
    CH(B[0].y, B[2].y, B[4].y, B[6].y, (C) + 1, 1);                            \
    CH(B[0].z, B[2].z, B[4].z, B[6].z, (C) + 2, 2);                            \
    CH(B[0].w, B[2].w, B[4].w, B[6].w, (C) + 3, 3);                            \
    CH(B[1].x, B[3].x, B[5].x, B[7].x, (C) + 4, 0);                            \
    CH(B[1].y, B[3].y, B[5].y, B[7].y, (C) + 5, 1);                            \
    CH(B[1].z, B[3].z, B[5].z, B[7].z, (C) + 6, 2);                            \
    CH(B[1].w, B[3].w, B[5].w, B[7].w, (C) + 7, 3);                            \
  }
    float4 A[8], B[8];
    LOADB(A, 0);
#pragma unroll
    for (int k = 0; k < 16; k += 2) {  // 16 batches of 8 channels, dbuf
      LOADB(B, 8 * (k + 1));           // batch k+1 in flight...
      COMPB(A, 8 * k);                 // ...while computing batch k
      if (k + 2 < 16) LOADB(A, 8 * (k + 2));
      COMPB(B, 8 * (k + 1));
    }
#undef COMPB
#undef LOADB
#undef CH
    // exact merge: global max; on value tie, smallest channel index wins
    m0 = ms0[0]; am0 = as0[0]; m1 = ms1[0]; am1 = as1[0];
#pragma unroll
    for (int j = 1; j < 4; ++j) {
      if (ms0[j] > m0 || (ms0[j] == m0 && as0[j] < am0)) { m0 = ms0[j]; am0 = as0[j]; }
      if (ms1[j] > m1 || (ms1[j] == m1 && as1[j] < am1)) { m1 = ms1[j]; am1 = as1[j]; }
    }
    T0 = (Ts0[0] + Ts0[1]) + (Ts0[2] + Ts0[3]);
    T1 = (Ts1[0] + Ts1[1]) + (Ts1[2] + Ts1[3]);
  } else {  // general path (never taken for this input; correctness only)
    unsigned long long mlo = ws_mask[0], mhi = ws_mask[1];
    float rm0 = -INFINITY, rm1 = -INFINITY;
#pragma unroll 4
    for (int c = 0; c < 128; ++c) {
      float a00 = P00[c], a01 = P01[c];
      float a10 = P10[c], a11 = P11[c];
      float r0 = a00 * iwy + a10 * wy;
      float r1 = a01 * iwy + a11 * wy;
      float v0 = r0 * iwx0 + r1 * wx0;
      float v1 = r0 * iwx1 + r1 * wx1;
      rm0 = fmaxf(rm0, v0);
      rm1 = fmaxf(rm1, v1);
      unsigned long long bit = (c < 64) ? (mlo >> c) : (mhi >> (c - 64));
      if (bit & 1) {  // wave-uniform branch
        bool g0 = v0 > m0; m0 = g0 ? v0 : m0; am0 = g0 ? c : am0;
        bool g1 = v1 > m1; m1 = g1 ? v1 : m1; am1 = g1 ? c : am1;
        T0 += __expf(v0);
        T1 += __expf(v1);
      }
    }
    dp0 = (rm0 == m0);
    dp1 = (rm1 == m1);
  }

  // ---- epilogue: conf > 0.4  <=>  exp(m) > 0.4*T  (T > 0, all v bounded)
  float cg0 = ((__expf(m0) > 0.4f * T0) && dp0) ? 1.0f : 0.0f;
  float cg1 = ((__expf(m1) > 0.4f * T1) && dp1) ? 1.0f : 0.0f;
  float sem0 = ws_cls[am0], sem1 = ws_cls[am1];  // L1/L2-cached tables
  float mid0 = (float)(ws_didx[am0] + 1), mid1 = (float)(ws_didx[am1] + 1);
  float th0 = (sem0 < 80.f) ? cg0 : 0.f;
  float st0 = cg0 - th0;
  float th1 = (sem1 < 80.f) ? cg1 : 0.f;
  float st1 = cg1 - th1;

  if (y < 641) {
    if (xa < 641) {
      int i0 = y * 641 + xa;
      out[i0] = mid0; out[NP + i0] = sem0; out[2 * NP + i0] = th0; out[3 * NP + i0] = st0;
    }
    if (xa + 1 < 641) {
      int i1 = y * 641 + xa + 1;
      out[i1] = mid1; out[NP + i1] = sem1; out[2 * NP + i1] = th1; out[3 * NP + i1] = st1;
    }
  }
}

extern "C" void kernel_launch(void* const* d_in, const int* in_sizes, int n_in,
                              void* d_out, int out_size, void* d_ws,
                              size_t ws_size, hipStream_t stream) {
  const float* logits = (const float*)d_in[0];  // (161,161,128) f32
  const float* probs = (const float*)d_in[1];   // (128,134) f32
  float* out = (float*)d_out;

  float* ws_f = (float*)d_ws;
  float* cls_pred = ws_f;                                    // 128 f32
  int* det_idx = (int*)(ws_f + 128);                         // 128 i32
  unsigned long long* det_mask = (unsigned long long*)(ws_f + 256);  // 2 u64
  int* num_det = (int*)(ws_f + 260);                         // 1 i32

  slot_kernel<<<1, 1024, 0, stream>>>(probs, cls_pred, det_idx, det_mask,
                                      num_det);

  // 1681 tiles (41x41 of 16x16), padded to 1688 = 8*211 for XCD banding.
  post_kernel<<<1688, 128, 0, stream>>>(logits, cls_pred, det_idx, det_mask,
                                        num_det, out);
}